// Round 3
// baseline (1098.525 us; speedup 1.0000x reference)
//
#include <hip/hip_runtime.h>
#include <hip/hip_bf16.h>

#define S 8192
#define D 1024
#define QBLK 32
#define NW 16
#define KW 32
#define KVBLK (NW*KW)    // 512
#define NITER (S/KVBLK)  // 16
#define NTHR (NW*64)     // 1024

typedef short short8 __attribute__((ext_vector_type(8)));
typedef float f32x16 __attribute__((ext_vector_type(16)));

__device__ __forceinline__ unsigned short f2bf(float x) {
    unsigned u = __builtin_bit_cast(unsigned, x);
    u += 0x7FFFu + ((u >> 16) & 1u);   // RNE
    return (unsigned short)(u >> 16);
}
__device__ __forceinline__ float fexp2(float x) { return __builtin_amdgcn_exp2f(x); }

// 16B logical read from a row with 8B-granule XOR swizzle (two ds_read_b64)
__device__ __forceinline__ short8 lds_r16(const char* rowbase, int off, int swz) {
    uint2 a = *(const uint2*)(rowbase + (off ^ swz));
    uint2 b = *(const uint2*)(rowbase + ((off + 8) ^ swz));
    int4 w; w.x = (int)a.x; w.y = (int)a.y; w.z = (int)b.x; w.w = (int)b.y;
    return __builtin_bit_cast(short8, w);
}
__device__ __forceinline__ void lds_w16(char* rowbase, int off, int swz, short8 v) {
    int4 w = __builtin_bit_cast(int4, v);
    uint2 a; a.x = (unsigned)w.x; a.y = (unsigned)w.y;
    uint2 b; b.x = (unsigned)w.z; b.y = (unsigned)w.w;
    *(uint2*)(rowbase + (off ^ swz))       = a;
    *(uint2*)(rowbase + ((off + 8) ^ swz)) = b;
}

// ---- prep: K fp32 -> bf16 (same layout) ----
__global__ void conv_k_kernel(const float* __restrict__ in, unsigned short* __restrict__ out) {
    size_t i = ((size_t)blockIdx.x * 256 + threadIdx.x) * 8;
    const float4* p4 = (const float4*)(in + i);
    float4 a = p4[0], b = p4[1];
    short8 v;
    v[0] = (short)f2bf(a.x); v[1] = (short)f2bf(a.y); v[2] = (short)f2bf(a.z); v[3] = (short)f2bf(a.w);
    v[4] = (short)f2bf(b.x); v[5] = (short)f2bf(b.y); v[6] = (short)f2bf(b.z); v[7] = (short)f2bf(b.w);
    *(short8*)(out + i) = v;
}

// ---- prep: V (S x D fp32) -> V^T (D x S bf16) ----
__global__ void transp_v_kernel(const float* __restrict__ in, unsigned short* __restrict__ out) {
    __shared__ float t[32][33];
    int k0 = blockIdx.x * 32, d0 = blockIdx.y * 32;
    int tx = threadIdx.x, ty = threadIdx.y;
#pragma unroll
    for (int i = 0; i < 4; ++i)
        t[ty + 8 * i][tx] = in[(size_t)(k0 + ty + 8 * i) * D + d0 + tx];
    __syncthreads();
#pragma unroll
    for (int i = 0; i < 4; ++i)
        out[(size_t)(d0 + ty + 8 * i) * S + k0 + tx] = f2bf(t[tx][ty + 8 * i]);
}

// ---- main fused attention: 16 waves, KVBLK=512, QBLK=32 ----
template<bool CONV>
__global__ __launch_bounds__(NTHR, 4)
void attn_kernel(const float* __restrict__ Qf,
                 const unsigned short* __restrict__ Kb,
                 const unsigned short* __restrict__ VTb,
                 const float* __restrict__ Kf,
                 const float* __restrict__ Vf,
                 float* __restrict__ Out)
{
    __shared__ unsigned short q_lds[QBLK * D];      // 64KB, 8B-swizzled rows of 2048B
    __shared__ unsigned short p_lds[QBLK * KVBLK];  // 32KB, 8B-swizzled rows of 1024B
    __shared__ float red_m[NW][QBLK];               // 2KB
    __shared__ float red_l[NW][QBLK];               // 2KB
    __shared__ float alpha_sh[QBLK];
    __shared__ float invl_sh[QBLK];

    const int tid  = threadIdx.x;
    const int wid  = tid >> 6;
    const int lane = tid & 63;
    const int ln31 = lane & 31;
    const int hi   = (lane >> 5) & 1;
    const int q0   = blockIdx.x * QBLK;
    const int swz  = (ln31 & 15) << 3;   // 8B-granule swizzle: 16-row spread -> 2-way max

    // ---- stage Q into LDS, scaled by log2(e)/sqrt(D), swizzled ----
    {
        const float cscale = 1.44269504088896340736f / 32.0f;
        const float* qg = Qf + (size_t)q0 * D;
        char* qb = (char*)q_lds;
#pragma unroll
        for (int it = 0; it < (QBLK * D) / (NTHR * 8); ++it) {
            int idx = (it * NTHR + tid) * 8;
            int qq = idx >> 10, dd = idx & (D - 1);
            const float4* p4 = (const float4*)(qg + idx);
            float4 a = p4[0], b = p4[1];
            short8 v;
            v[0] = (short)f2bf(a.x * cscale); v[1] = (short)f2bf(a.y * cscale);
            v[2] = (short)f2bf(a.z * cscale); v[3] = (short)f2bf(a.w * cscale);
            v[4] = (short)f2bf(b.x * cscale); v[5] = (short)f2bf(b.y * cscale);
            v[6] = (short)f2bf(b.z * cscale); v[7] = (short)f2bf(b.w * cscale);
            lds_w16(qb + qq * 2048, dd * 2, (qq & 15) << 3, v);
        }
    }

    f32x16 O0, O1;
#pragma unroll
    for (int i = 0; i < 16; ++i) { O0[i] = 0.f; O1[i] = 0.f; }
    float m_run = -1e30f, l_run = 0.f;

    __syncthreads();

    for (int t = 0; t < NITER; ++t) {
        const int kbase = t * KVBLK;
        const int krow  = kbase + wid * KW + ln31;

        // ---------- scores: S^T = K_w . Q^T (64 MFMA, 2 acc chains) ----------
        f32x16 s0, s1;
#pragma unroll
        for (int i = 0; i < 16; ++i) { s0[i] = 0.f; s1[i] = 0.f; }

        const char* qb = (const char*)q_lds + ln31 * 2048;
        __builtin_amdgcn_s_setprio(1);
        if (CONV) {
            const unsigned short* kg = Kb + (size_t)krow * D + hi * 8;
#pragma unroll 4
            for (int kk = 0; kk < 64; kk += 2) {
                short8 a0 = *(const short8*)(kg + kk * 16);
                short8 b0 = lds_r16(qb, kk * 32 + hi * 16, swz);
                s0 = __builtin_amdgcn_mfma_f32_32x32x16_bf16(a0, b0, s0, 0, 0, 0);
                short8 a1 = *(const short8*)(kg + (kk + 1) * 16);
                short8 b1 = lds_r16(qb, (kk + 1) * 32 + hi * 16, swz);
                s1 = __builtin_amdgcn_mfma_f32_32x32x16_bf16(a1, b1, s1, 0, 0, 0);
            }
        } else {
            const float* kg = Kf + (size_t)krow * D + hi * 8;
#pragma unroll 2
            for (int kk = 0; kk < 64; ++kk) {
                const float4* f4 = (const float4*)(kg + kk * 16);
                float4 x = f4[0], y = f4[1];
                short8 a0;
                a0[0] = (short)f2bf(x.x); a0[1] = (short)f2bf(x.y); a0[2] = (short)f2bf(x.z); a0[3] = (short)f2bf(x.w);
                a0[4] = (short)f2bf(y.x); a0[5] = (short)f2bf(y.y); a0[6] = (short)f2bf(y.z); a0[7] = (short)f2bf(y.w);
                short8 b0 = lds_r16(qb, kk * 32 + hi * 16, swz);
                s0 = __builtin_amdgcn_mfma_f32_32x32x16_bf16(a0, b0, s0, 0, 0, 0);
            }
        }
        __builtin_amdgcn_s_setprio(0);
#pragma unroll
        for (int i = 0; i < 16; ++i) s0[i] += s1[i];

        // ---------- softmax (exp2 domain; scale folded into Q) ----------
        float mloc = s0[0];
#pragma unroll
        for (int r = 1; r < 16; ++r) mloc = fmaxf(mloc, s0[r]);
        mloc = fmaxf(mloc, __shfl_xor(mloc, 32));
        if (lane < 32) red_m[wid][ln31] = mloc;
        __syncthreads();                       // bar A

        float mt = red_m[0][ln31];
#pragma unroll
        for (int w = 1; w < NW; ++w) mt = fmaxf(mt, red_m[w][ln31]);
        float mnew  = fmaxf(m_run, mt);
        float alpha = fexp2(m_run - mnew);

        float pr[16];
        float lloc = 0.f;
#pragma unroll
        for (int r = 0; r < 16; ++r) { pr[r] = fexp2(s0[r] - mnew); lloc += pr[r]; }
        lloc += __shfl_xor(lloc, 32);
        if (lane < 32) { red_l[wid][ln31] = lloc; if (wid == 0) alpha_sh[ln31] = alpha; }

        {   // pack P -> bf16, swizzled write (true k slot = (reg&3)+8*(reg>>2)+4*hi)
            char* pb = (char*)p_lds + ln31 * 1024;
#pragma unroll
            for (int g = 0; g < 4; ++g) {
                unsigned p01 = (unsigned)f2bf(pr[4 * g + 0]) | ((unsigned)f2bf(pr[4 * g + 1]) << 16);
                unsigned p23 = (unsigned)f2bf(pr[4 * g + 2]) | ((unsigned)f2bf(pr[4 * g + 3]) << 16);
                uint2 val = make_uint2(p01, p23);
                int koff = (wid * 32 + 8 * g + 4 * hi) * 2;   // 8B-aligned
                *(uint2*)(pb + (koff ^ swz)) = val;
            }
        }
        __syncthreads();                       // bar B

        float lsum = red_l[0][ln31];
#pragma unroll
        for (int w = 1; w < NW; ++w) lsum += red_l[w][ln31];
        l_run = l_run * alpha + lsum;
        m_run = mnew;

        // ---------- rescale O by alpha at this lane's q-rows ----------
#pragma unroll
        for (int r = 0; r < 16; ++r) {
            float ar = alpha_sh[(r & 3) + 8 * (r >> 2) + 4 * hi];
            O0[r] *= ar; O1[r] *= ar;
        }

        // ---------- PV: O += P . V  (64 MFMA, 2 acc chains) ----------
        const char* pbase = (const char*)p_lds + ln31 * 1024;
        __builtin_amdgcn_s_setprio(1);
        if (CONV) {
            const unsigned short* vg = VTb + (size_t)(wid * 64 + ln31) * S + kbase + hi * 8;
#pragma unroll 4
            for (int kstep = 0; kstep < 32; ++kstep) {
                short8 pa = lds_r16(pbase, kstep * 32 + hi * 16, swz);
                short8 v0 = *(const short8*)(vg + kstep * 16);
                O0 = __builtin_amdgcn_mfma_f32_32x32x16_bf16(pa, v0, O0, 0, 0, 0);
                short8 v1 = *(const short8*)(vg + (size_t)32 * S + kstep * 16);
                O1 = __builtin_amdgcn_mfma_f32_32x32x16_bf16(pa, v1, O1, 0, 0, 0);
            }
        } else {
            const float* vf = Vf + (size_t)(kbase + hi * 8) * D + wid * 64 + ln31;
#pragma unroll 2
            for (int kstep = 0; kstep < 32; ++kstep) {
                short8 pa = lds_r16(pbase, kstep * 32 + hi * 16, swz);
#pragma unroll
                for (int f = 0; f < 2; ++f) {
                    short8 vb;
#pragma unroll
                    for (int j = 0; j < 8; ++j)
                        vb[j] = (short)f2bf(vf[(size_t)(kstep * 16 + j) * D + f * 32]);
                    if (f == 0) O0 = __builtin_amdgcn_mfma_f32_32x32x16_bf16(pa, vb, O0, 0, 0, 0);
                    else        O1 = __builtin_amdgcn_mfma_f32_32x32x16_bf16(pa, vb, O1, 0, 0, 0);
                }
            }
        }
        __builtin_amdgcn_s_setprio(0);
        // next iter's p_lds/red writes are fenced by bar A of next iteration
    }

    // ---------- epilogue: O /= l ----------
    if (wid == 0 && lane < 32) invl_sh[ln31] = 1.0f / l_run;
    __syncthreads();

    float* outp = Out + (size_t)q0 * D + wid * 64 + ln31;
#pragma unroll
    for (int r = 0; r < 16; ++r) {
        int qrow = (r & 3) + 8 * (r >> 2) + 4 * hi;
        float inv = invl_sh[qrow];
        outp[(size_t)qrow * D + 0]  = O0[r] * inv;
        outp[(size_t)qrow * D + 32] = O1[r] * inv;
    }
}

extern "C" void kernel_launch(void* const* d_in, const int* in_sizes, int n_in,
                              void* d_out, int out_size, void* d_ws, size_t ws_size,
                              hipStream_t stream)
{
    const float* q = (const float*)d_in[0];
    const float* k = (const float*)d_in[1];
    const float* v = (const float*)d_in[2];
    float* out = (float*)d_out;

    const size_t need = (size_t)2 * S * D * sizeof(unsigned short);  // 33.6 MB
    if (ws_size >= need) {
        unsigned short* kb = (unsigned short*)d_ws;
        unsigned short* vt = kb + (size_t)S * D;
        hipLaunchKernelGGL(conv_k_kernel, dim3(S * D / (256 * 8)), dim3(256), 0, stream, k, kb);
        hipLaunchKernelGGL(transp_v_kernel, dim3(S / 32, D / 32), dim3(32, 8), 0, stream, v, vt);
        hipLaunchKernelGGL((attn_kernel<true>), dim3(S / QBLK), dim3(NTHR), 0, stream,
                           q, kb, vt, (const float*)nullptr, (const float*)nullptr, out);
    } else {
        hipLaunchKernelGGL((attn_kernel<false>), dim3(S / QBLK), dim3(NTHR), 0, stream,
                           q, (const unsigned short*)nullptr, (const unsigned short*)nullptr, k, v, out);
    }
}

// Round 6
// 633.541 us; speedup vs baseline: 1.7339x; 1.7339x over previous
//
#include <hip/hip_runtime.h>
#include <hip/hip_bf16.h>

#define S 8192
#define D 1024
#define QBLK 32
#define NW 8
#define KVBLK 256        // 8 waves x 32 k-rows
#define NITER (S/KVBLK)  // 32
#define NTHR (NW*64)     // 512

typedef short short8 __attribute__((ext_vector_type(8)));
typedef float f32x16 __attribute__((ext_vector_type(16)));

__device__ __forceinline__ unsigned short f2bf(float x) {
    unsigned u = __builtin_bit_cast(unsigned, x);
    u += 0x7FFFu + ((u >> 16) & 1u);   // RNE
    return (unsigned short)(u >> 16);
}
__device__ __forceinline__ float fexp2(float x) { return __builtin_amdgcn_exp2f(x); }

// 16B logical LDS read/write with 8B-granule XOR swizzle (two b64 ops)
__device__ __forceinline__ short8 lds_r16(const char* rowbase, int off, int swz) {
    uint2 a = *(const uint2*)(rowbase + (off ^ swz));
    uint2 b = *(const uint2*)(rowbase + ((off + 8) ^ swz));
    int4 w; w.x = (int)a.x; w.y = (int)a.y; w.z = (int)b.x; w.w = (int)b.y;
    return __builtin_bit_cast(short8, w);
}
__device__ __forceinline__ void lds_w16(char* rowbase, int off, int swz, short8 v) {
    int4 w = __builtin_bit_cast(int4, v);
    uint2 a; a.x = (unsigned)w.x; a.y = (unsigned)w.y;
    uint2 b; b.x = (unsigned)w.z; b.y = (unsigned)w.w;
    *(uint2*)(rowbase + (off ^ swz))       = a;
    *(uint2*)(rowbase + ((off + 8) ^ swz)) = b;
}

// ---- prep: K fp32 [S][D] -> fragment-ordered bf16 ----
// out[ ((kt*64 + dc)*64 + lane)*8 + j ] = K[kt*32 + (lane&31)][dc*16 + (lane>>5)*8 + j]
// A wave's QK A-fragment (k-tile kt, d-chunk dc) is then 1KB contiguous.
__global__ void pack_k_kernel(const float* __restrict__ in, unsigned short* __restrict__ out) {
    int idx  = blockIdx.x * 256 + threadIdx.x;       // 0 .. S*D/8
    int lane = idx & 63, dc = (idx >> 6) & 63, kt = idx >> 12;
    int row = kt * 32 + (lane & 31), col = dc * 16 + (lane >> 5) * 8;
    const float4* p = (const float4*)(in + (size_t)row * D + col);
    float4 a = p[0], b = p[1];
    short8 v;
    v[0] = (short)f2bf(a.x); v[1] = (short)f2bf(a.y); v[2] = (short)f2bf(a.z); v[3] = (short)f2bf(a.w);
    v[4] = (short)f2bf(b.x); v[5] = (short)f2bf(b.y); v[6] = (short)f2bf(b.z); v[7] = (short)f2bf(b.w);
    *(short8*)(out + (size_t)idx * 8) = v;
}

// ---- prep: V fp32 [S][D] -> fragment-ordered (transposed) bf16 ----
// out[ (((t*16 + kc)*32 + db)*64 + lane)*8 + j ] = V[t*256 + kc*16 + (lane>>5)*8 + j][db*32 + (lane&31)]
// A wave's PV B-fragment (kv-tile t, k-step kc, d-block db) is 1KB contiguous.
__global__ void pack_v_kernel(const float* __restrict__ in, unsigned short* __restrict__ out) {
    int idx  = blockIdx.x * 256 + threadIdx.x;       // 0 .. S*D/8
    int lane = idx & 63, db = (idx >> 6) & 31, kc = (idx >> 11) & 15, t = idx >> 15;
    int col = db * 32 + (lane & 31);
    int rowbase = t * 256 + kc * 16 + (lane >> 5) * 8;
    short8 v;
#pragma unroll
    for (int j = 0; j < 8; ++j)
        v[j] = (short)f2bf(in[(size_t)(rowbase + j) * D + col]);
    *(short8*)(out + (size_t)idx * 8) = v;
}

// ---- main fused attention: 8 waves, KVBLK=256, QBLK=32, packed coalesced K/V streams ----
template<bool CONV>
__global__ __launch_bounds__(NTHR, 2)
void attn_kernel(const float* __restrict__ Qf,
                 const unsigned short* __restrict__ Kpk,
                 const unsigned short* __restrict__ Vpk,
                 const float* __restrict__ Kf,
                 const float* __restrict__ Vf,
                 float* __restrict__ Out)
{
    __shared__ unsigned short q_lds[QBLK * D];      // 64KB, swizzled rows of 2048B
    __shared__ unsigned short p_lds[QBLK * KVBLK];  // 16KB, swizzled rows of 512B
    __shared__ float red_m[NW][QBLK];
    __shared__ float red_l[NW][QBLK];
    __shared__ float alpha_sh[QBLK];
    __shared__ float invl_sh[QBLK];

    const int tid  = threadIdx.x;
    const int wid  = tid >> 6;
    const int lane = tid & 63;
    const int ln31 = lane & 31;
    const int hi   = (lane >> 5) & 1;
    const int q0   = blockIdx.x * QBLK;
    const int swz  = (ln31 & 15) << 3;

    // ---- stage Q into LDS, scaled by log2(e)/sqrt(D), swizzled ----
    {
        const float cscale = 1.44269504088896340736f / 32.0f;
        const float* qg = Qf + (size_t)q0 * D;
        char* qb = (char*)q_lds;
#pragma unroll
        for (int it = 0; it < (QBLK * D) / (NTHR * 8); ++it) {
            int idx = (it * NTHR + tid) * 8;
            int qq = idx >> 10, dd = idx & (D - 1);
            const float4* p4 = (const float4*)(qg + idx);
            float4 a = p4[0], b = p4[1];
            short8 v;
            v[0] = (short)f2bf(a.x * cscale); v[1] = (short)f2bf(a.y * cscale);
            v[2] = (short)f2bf(a.z * cscale); v[3] = (short)f2bf(a.w * cscale);
            v[4] = (short)f2bf(b.x * cscale); v[5] = (short)f2bf(b.y * cscale);
            v[6] = (short)f2bf(b.z * cscale); v[7] = (short)f2bf(b.w * cscale);
            lds_w16(qb + qq * 2048, dd * 2, (qq & 15) << 3, v);
        }
    }

    f32x16 O0, O1, O2, O3;
#pragma unroll
    for (int i = 0; i < 16; ++i) { O0[i] = 0.f; O1[i] = 0.f; O2[i] = 0.f; O3[i] = 0.f; }
    float m_run = -1e30f, l_run = 0.f;

    __syncthreads();

    for (int t = 0; t < NITER; ++t) {
        // ---------- scores: S^T = K_w . Q^T (64 MFMA, 2 acc chains) ----------
        f32x16 s0, s1;
#pragma unroll
        for (int i = 0; i < 16; ++i) { s0[i] = 0.f; s1[i] = 0.f; }

        const char* qb = (const char*)q_lds + ln31 * 2048;
        __builtin_amdgcn_s_setprio(1);
        if (CONV) {
            // fragment stream: frag = (t*8+wid)*4096 + dc*64 + lane — fully coalesced
            const unsigned short* kg = Kpk + ((size_t)(t * 8 + wid) * 4096 + lane) * 8;
#pragma unroll 8
            for (int dc = 0; dc < 64; dc += 2) {
                short8 a0 = *(const short8*)(kg + (size_t)dc * 512);
                short8 b0 = lds_r16(qb, dc * 32 + hi * 16, swz);
                s0 = __builtin_amdgcn_mfma_f32_32x32x16_bf16(a0, b0, s0, 0, 0, 0);
                short8 a1 = *(const short8*)(kg + (size_t)(dc + 1) * 512);
                short8 b1 = lds_r16(qb, (dc + 1) * 32 + hi * 16, swz);
                s1 = __builtin_amdgcn_mfma_f32_32x32x16_bf16(a1, b1, s1, 0, 0, 0);
            }
        } else {
            const int krow = t * KVBLK + wid * 32 + ln31;
            const float* kg = Kf + (size_t)krow * D + hi * 8;
#pragma unroll 2
            for (int dc = 0; dc < 64; ++dc) {
                const float4* f4 = (const float4*)(kg + dc * 16);
                float4 x = f4[0], y = f4[1];
                short8 a0;
                a0[0] = (short)f2bf(x.x); a0[1] = (short)f2bf(x.y); a0[2] = (short)f2bf(x.z); a0[3] = (short)f2bf(x.w);
                a0[4] = (short)f2bf(y.x); a0[5] = (short)f2bf(y.y); a0[6] = (short)f2bf(y.z); a0[7] = (short)f2bf(y.w);
                short8 b0 = lds_r16(qb, dc * 32 + hi * 16, swz);
                s0 = __builtin_amdgcn_mfma_f32_32x32x16_bf16(a0, b0, s0, 0, 0, 0);
            }
        }
        __builtin_amdgcn_s_setprio(0);
#pragma unroll
        for (int i = 0; i < 16; ++i) s0[i] += s1[i];

        // ---------- online softmax (exp2 domain; scale folded into Q) ----------
        float mloc = s0[0];
#pragma unroll
        for (int r = 1; r < 16; ++r) mloc = fmaxf(mloc, s0[r]);
        mloc = fmaxf(mloc, __shfl_xor(mloc, 32));
        if (lane < 32) red_m[wid][ln31] = mloc;
        __syncthreads();                       // bar A

        float mt = red_m[0][ln31];
#pragma unroll
        for (int w = 1; w < NW; ++w) mt = fmaxf(mt, red_m[w][ln31]);
        float mnew  = fmaxf(m_run, mt);
        float alpha = fexp2(m_run - mnew);

        float pr[16];
        float lloc = 0.f;
#pragma unroll
        for (int r = 0; r < 16; ++r) { pr[r] = fexp2(s0[r] - mnew); lloc += pr[r]; }
        lloc += __shfl_xor(lloc, 32);
        if (lane < 32) { red_l[wid][ln31] = lloc; if (wid == 0) alpha_sh[ln31] = alpha; }

        {   // pack P -> bf16, swizzled LDS write (k slot = (r&3)+8*(r>>2)+4*hi)
            char* pb = (char*)p_lds + ln31 * 512;
#pragma unroll
            for (int g = 0; g < 4; ++g) {
                unsigned p01 = (unsigned)f2bf(pr[4 * g + 0]) | ((unsigned)f2bf(pr[4 * g + 1]) << 16);
                unsigned p23 = (unsigned)f2bf(pr[4 * g + 2]) | ((unsigned)f2bf(pr[4 * g + 3]) << 16);
                uint2 val = make_uint2(p01, p23);
                int koff = (wid * 32 + 8 * g + 4 * hi) * 2;   // 8B-aligned
                *(uint2*)(pb + (koff ^ swz)) = val;
            }
        }
        __syncthreads();                       // bar B

        float lsum = red_l[0][ln31];
#pragma unroll
        for (int w = 1; w < NW; ++w) lsum += red_l[w][ln31];
        l_run = l_run * alpha + lsum;
        m_run = mnew;

        // ---------- rescale O by alpha at this lane's q-rows ----------
#pragma unroll
        for (int r = 0; r < 16; ++r) {
            float ar = alpha_sh[(r & 3) + 8 * (r >> 2) + 4 * hi];
            O0[r] *= ar; O1[r] *= ar; O2[r] *= ar; O3[r] *= ar;
        }

        // ---------- PV: O += P . V  (64 MFMA, 4 acc chains) ----------
        const char* pbase = (const char*)p_lds + ln31 * 512;
        __builtin_amdgcn_s_setprio(1);
        if (CONV) {
            // frag = (t*16+kc)*2048 + (wid + 8*f)*64 + lane — fully coalesced
            // BUGFIX R5: wave base is wid*64 frags (was wid*512 = 8x too far)
            const unsigned short* vg = Vpk + ((size_t)(t * 16) * 2048 + (size_t)wid * 64 + lane) * 8;
#pragma unroll 4
            for (int kc = 0; kc < 16; ++kc) {
                short8 pa = lds_r16(pbase, kc * 32 + hi * 16, swz);
                const unsigned short* vk = vg + (size_t)kc * 16384;    // kc stride = 2048 frags
                short8 v0 = *(const short8*)(vk);
                O0 = __builtin_amdgcn_mfma_f32_32x32x16_bf16(pa, v0, O0, 0, 0, 0);
                short8 v1 = *(const short8*)(vk + 4096);               // f stride = 512 frags
                O1 = __builtin_amdgcn_mfma_f32_32x32x16_bf16(pa, v1, O1, 0, 0, 0);
                short8 v2 = *(const short8*)(vk + 8192);
                O2 = __builtin_amdgcn_mfma_f32_32x32x16_bf16(pa, v2, O2, 0, 0, 0);
                short8 v3 = *(const short8*)(vk + 12288);
                O3 = __builtin_amdgcn_mfma_f32_32x32x16_bf16(pa, v3, O3, 0, 0, 0);
            }
        } else {
            const int dcol0 = wid * 32 + ln31;
#pragma unroll 2
            for (int kc = 0; kc < 16; ++kc) {
                short8 pa = lds_r16(pbase, kc * 32 + hi * 16, swz);
                const float* vf = Vf + (size_t)(t * 256 + kc * 16 + hi * 8) * D + dcol0;
#pragma unroll
                for (int f = 0; f < 4; ++f) {
                    short8 vb;
#pragma unroll
                    for (int j = 0; j < 8; ++j)
                        vb[j] = (short)f2bf(vf[(size_t)j * D + f * 256]);
                    if (f == 0) O0 = __builtin_amdgcn_mfma_f32_32x32x16_bf16(pa, vb, O0, 0, 0, 0);
                    if (f == 1) O1 = __builtin_amdgcn_mfma_f32_32x32x16_bf16(pa, vb, O1, 0, 0, 0);
                    if (f == 2) O2 = __builtin_amdgcn_mfma_f32_32x32x16_bf16(pa, vb, O2, 0, 0, 0);
                    if (f == 3) O3 = __builtin_amdgcn_mfma_f32_32x32x16_bf16(pa, vb, O3, 0, 0, 0);
                }
            }
        }
        __builtin_amdgcn_s_setprio(0);
    }

    // ---------- epilogue: O /= l ----------
    if (wid == 0 && lane < 32) invl_sh[ln31] = 1.0f / l_run;
    __syncthreads();

    float* outp = Out + (size_t)q0 * D + wid * 32 + ln31;
#pragma unroll
    for (int r = 0; r < 16; ++r) {
        int qrow = (r & 3) + 8 * (r >> 2) + 4 * hi;
        float inv = invl_sh[qrow];
        outp[(size_t)qrow * D + 0]   = O0[r] * inv;
        outp[(size_t)qrow * D + 256] = O1[r] * inv;
        outp[(size_t)qrow * D + 512] = O2[r] * inv;
        outp[(size_t)qrow * D + 768] = O3[r] * inv;
    }
}

extern "C" void kernel_launch(void* const* d_in, const int* in_sizes, int n_in,
                              void* d_out, int out_size, void* d_ws, size_t ws_size,
                              hipStream_t stream)
{
    const float* q = (const float*)d_in[0];
    const float* k = (const float*)d_in[1];
    const float* v = (const float*)d_in[2];
    float* out = (float*)d_out;

    const size_t need = (size_t)2 * S * D * sizeof(unsigned short);  // 33.6 MB
    if (ws_size >= need) {
        unsigned short* kpk = (unsigned short*)d_ws;
        unsigned short* vpk = kpk + (size_t)S * D;
        hipLaunchKernelGGL(pack_k_kernel, dim3(S * D / (256 * 8)), dim3(256), 0, stream, k, kpk);
        hipLaunchKernelGGL(pack_v_kernel, dim3(S * D / (256 * 8)), dim3(256), 0, stream, v, vpk);
        hipLaunchKernelGGL((attn_kernel<true>), dim3(S / QBLK), dim3(NTHR), 0, stream,
                           q, kpk, vpk, (const float*)nullptr, (const float*)nullptr, out);
    } else {
        hipLaunchKernelGGL((attn_kernel<false>), dim3(S / QBLK), dim3(NTHR), 0, stream,
                           q, (const unsigned short*)nullptr, (const unsigned short*)nullptr, k, v, out);
    }
}